// Round 3
// baseline (188.202 us; speedup 1.0000x reference)
//
#include <hip/hip_runtime.h>
#include <math.h>

#define N 8192
#define D 128
#define NT 64                    // 128-wide tiles per dim
#define NBLK (NT * (NT + 1) / 2) // 2080

typedef __attribute__((ext_vector_type(8))) short bf8;   // 8 bf16 = 4 VGPRs
typedef __attribute__((ext_vector_type(4))) float f4;    // MFMA acc

__device__ __forceinline__ unsigned short bf16_rtne(float f) {
    unsigned u = __float_as_uint(f);
    u += 0x7FFF + ((u >> 16) & 1);
    return (unsigned short)(u >> 16);
}
__device__ __forceinline__ float bf16_tof(unsigned short h) {
    return __uint_as_float((unsigned)h << 16);
}

__device__ __forceinline__ void async_cp16(const void* g, void* l) {
    __builtin_amdgcn_global_load_lds(
        (const __attribute__((address_space(1))) unsigned*)g,
        (__attribute__((address_space(3))) unsigned*)l, 16, 0, 0);
}

// ---------------------------------------------------------------------------
// Kernel 1: normalize + 3-limb bf16 split; 32 rows/block. (unchanged, verified)
// ---------------------------------------------------------------------------
__global__ __launch_bounds__(256) void prep_kernel(
    const float* __restrict__ x, short* __restrict__ H,
    float* __restrict__ sq,
    unsigned long long* __restrict__ pos_pack,
    unsigned long long* __restrict__ neg_pack) {
    __shared__ float Xs[32 * 129];
    const int t = threadIdx.x;
    const int r0 = blockIdx.x * 32;

    if (t < 32) { pos_pack[r0 + t] = 0ULL; neg_pack[r0 + t] = ~0ULL; }

#pragma unroll
    for (int p = 0; p < 4; ++p) {
        const int lin = p * 256 + t;
        const int row = lin >> 5;
        const int c0 = (lin & 31) << 2;
        const float4 v = *(const float4*)(x + (size_t)(r0 + row) * D + c0);
        float* dst = &Xs[row * 129 + c0];
        dst[0] = v.x; dst[1] = v.y; dst[2] = v.z; dst[3] = v.w;
    }
    __syncthreads();

    const int r = t >> 3, q8 = t & 7;
    float* src = &Xs[r * 129 + q8 * 16];
    float s = 0.f;
#pragma unroll
    for (int i = 0; i < 16; ++i) s = fmaf(src[i], src[i], s);
    s += __shfl_xor(s, 1, 64);
    s += __shfl_xor(s, 2, 64);
    s += __shfl_xor(s, 4, 64);
    const float nrm = sqrtf(s);
    float t2 = 0.f;
#pragma unroll
    for (int i = 0; i < 16; ++i) {
        const float n = src[i] / nrm;
        src[i] = n;
        t2 = fmaf(n, n, t2);
    }
    t2 += __shfl_xor(t2, 1, 64);
    t2 += __shfl_xor(t2, 2, 64);
    t2 += __shfl_xor(t2, 4, 64);
    if (q8 == 0) sq[r0 + r] = t2;

    const size_t gbase = (size_t)(r0 + r) * D + q8 * 16;
#pragma unroll
    for (int g = 0; g < 4; ++g) {
        short4 o1, o2, o3;
        short* p1 = (short*)&o1; short* p2 = (short*)&o2; short* p3 = (short*)&o3;
#pragma unroll
        for (int i = 0; i < 4; ++i) {
            const float n = src[g * 4 + i];
            const unsigned short h1 = bf16_rtne(n);
            const float r1 = n - bf16_tof(h1);
            const unsigned short h2 = bf16_rtne(r1);
            const float r2 = r1 - bf16_tof(h2);
            const unsigned short h3 = bf16_rtne(r2);
            p1[i] = (short)h1; p2[i] = (short)h2; p3[i] = (short)h3;
        }
        *(short4*)(H + gbase + g * 4)                     = o1;
        *(short4*)(H + (size_t)N * D + gbase + g * 4)     = o2;
        *(short4*)(H + (size_t)2 * N * D + gbase + g * 4) = o3;
    }
}

// ---------------------------------------------------------------------------
// Kernel 2: symmetric 128x128-tile Gram via 3-limb bf16 mfma_16x16x32.
// R16: pipe-throughput fix (R15 post-mortem: sum of MFMA+VALU+DS pipe work
// ~90us with poor overlap at ~2 blocks/CU; VGPR 112 + AGPR 64 = 176/wave
// and 51.2KB LDS both capped residency).
//  - B-limb2 dropped from LDS: fed global->reg (bG2[8], single-buffered,
//    re-issued per-ct mid-sweep => near-full-sweep latency cover). The
//    (a0,b2) MFMA becomes pure-register.
//  - LDS 51.2 -> 34.8 KB (+1 resident block/CU); K-loop ds_read_b128
//    24 -> 16 per wave-chunk (-33% DS pipe); DMA 6 -> 4 per chunk.
//  - vmcnt(10) at chunk top drains {stage(q), aF(q), bG2(q)} (all >= one
//    sweep old), keeps {stage(q+1), aF(q+1)} in flight.
// Per-accumulator product order bitwise-identical to the verified kernel:
// a0b0, a0b1, a0b2, a1b0, a1b1, a2b0 per chunk, chunks in order.
// ---------------------------------------------------------------------------
__device__ __forceinline__ unsigned int fbits(float f) {
    union { float f; unsigned int u; } x; x.f = f; return x.u;
}
__device__ __forceinline__ unsigned long long pack_pos(float v, int j) {
    return ((unsigned long long)fbits(v) << 32) | (unsigned int)(8191 - j);
}
__device__ __forceinline__ unsigned long long pack_neg(float v, int j) {
    return ((unsigned long long)fbits(v) << 32) | (unsigned int)j;
}
__device__ __forceinline__ void red_max(float& v, int& j, int mask) {
    const float ov = __shfl_xor(v, mask, 64);
    const int   oj = __shfl_xor(j, mask, 64);
    if (ov > v || (ov == v && oj < j)) { v = ov; j = oj; }
}
__device__ __forceinline__ void red_min(float& v, int& j, int mask) {
    const float ov = __shfl_xor(v, mask, 64);
    const int   oj = __shfl_xor(j, mask, 64);
    if (ov < v || (ov == v && oj < j)) { v = ov; j = oj; }
}

__global__ __launch_bounds__(256) void miner_kernel(
    const short* __restrict__ H, const float* __restrict__ sq,
    const int* __restrict__ labels,
    unsigned long long* __restrict__ pos_pack,
    unsigned long long* __restrict__ neg_pack) {
    // B double-buffer: [2][2 limb][128 smp][32 k] shorts = 32768 B.
    __shared__ __align__(16) short sB[2 * 8192];
    __shared__ float sqS[256];   // [0:128)=sqI, [128:256)=sqJ
    __shared__ int   lbS[256];   // [0:128)=lbI, [128:256)=lbJ

    const int t = threadIdx.x;
    const int w = t >> 6;       // wave id: rows w*32..w*32+31
    const int l = t & 63;
    const int quad = l >> 4;
    const int l16 = l & 15;

    // decode upper-triangular (bi, bj), bi <= bj, NT=64
    const int b = blockIdx.x;
    int bi = (int)((129.0f - sqrtf(16641.0f - 8.0f * (float)b)) * 0.5f);
    while (bi > 0 && (bi * NT - bi * (bi - 1) / 2) > b) --bi;
    while (((bi + 1) * NT - (bi + 1) * bi / 2) <= b) ++bi;
    const int bj = bi + (b - (bi * NT - bi * (bi - 1) / 2));
    const int I0 = bi * 128, J0 = bj * 128;
    const bool diag = (bi == bj);

    // sq/labels prefetch: latency hidden under the entire K-loop
    float psq; int plb;
    {
        const int idx = ((t < 128) ? I0 : J0) + (t & 127);
        psq = sq[idx]; plb = labels[idx];
    }

    // B staging offsets: 4 x 16B per thread per chunk (limbs 0,1).
    int gOffB[4], lOffB[4];
#pragma unroll
    for (int p = 0; p < 4; ++p) {
        const int limb = p >> 1;
        const int c2   = (p & 1) * 256 + t;
        const int smp  = c2 >> 2;
        const int sub  = c2 & 3;
        gOffB[p] = limb * (N * D) + (J0 + smp) * D + sub * 8;
        lOffB[p] = (limb * 128 + smp) * 32 + sub * 8;
    }
    // A fragment global offsets, evens only (rt=1 derived: +16*D = 2048)
    int aGoff[3];
#pragma unroll
    for (int la = 0; la < 3; ++la)
        aGoff[la] = la * (N * D) + (I0 + w * 32 + l16) * D + quad * 8;
    // B-limb2 fragment base (ct stride = 16*D = 2048 elements)
    const int bG2base = 2 * (N * D) + (J0 + l16) * D + quad * 8;

    f4 acc[2][8];
#pragma unroll
    for (int rt = 0; rt < 2; ++rt)
#pragma unroll
        for (int ct = 0; ct < 8; ++ct) acc[rt][ct] = (f4){0.f, 0.f, 0.f, 0.f};

    // prologue: stage(0) DMA + aF(0) + bG2(0) reg loads
    bf8 aF[2][3][2];
    bf8 bG2[8];
#pragma unroll
    for (int p = 0; p < 4; ++p)
        async_cp16(H + (size_t)gOffB[p], sB + lOffB[p]);
#pragma unroll
    for (int la = 0; la < 3; ++la)
#pragma unroll
        for (int rt = 0; rt < 2; ++rt)
            aF[0][la][rt] = *(const bf8*)(H + (size_t)(aGoff[la] + rt * 2048));
#pragma unroll
    for (int ct = 0; ct < 8; ++ct)
        bG2[ct] = *(const bf8*)(H + (size_t)(bG2base + ct * 2048));

#pragma unroll
    for (int q = 0; q < 4; ++q) {
        const int cur = q & 1, nxt = cur ^ 1;
        const short* sBc = sB + cur * 8192;

        if (q < 3) {
            // issue next chunk's B-stage + A-frag loads (stay in flight
            // through this chunk's whole compute phase)
            short* sBn = sB + nxt * 8192;
            const int kn = (q + 1) * 32;
#pragma unroll
            for (int p = 0; p < 4; ++p)
                async_cp16(H + (size_t)(gOffB[p] + kn), sBn + lOffB[p]);
#pragma unroll
            for (int la = 0; la < 3; ++la)
#pragma unroll
                for (int rt = 0; rt < 2; ++rt)
                    aF[nxt][la][rt] =
                        *(const bf8*)(H + (size_t)(aGoff[la] + rt * 2048 + kn));
            // drain all but the newest 8 (= stage(q+1)+aF(q+1)); the drained
            // set {stage(q), aF(q), bG2(q)} was issued >= one sweep ago
            asm volatile("s_waitcnt vmcnt(8)" ::: "memory");
        } else {
            asm volatile("s_waitcnt vmcnt(0)" ::: "memory");
        }
        __builtin_amdgcn_s_barrier();          // all waves: sBc fully staged
        __builtin_amdgcn_sched_barrier(0);     // no ds_read hoisting above

        __builtin_amdgcn_s_setprio(1);
#pragma unroll
        for (int ct = 0; ct < 8; ++ct) {
            const bf8 bF0 = *(const bf8*)
                &sBc[(ct * 16 + l16) * 32 + quad * 8];
            const bf8 bF1 = *(const bf8*)
                &sBc[(128 + ct * 16 + l16) * 32 + quad * 8];
#pragma unroll
            for (int rt = 0; rt < 2; ++rt) {
                acc[rt][ct] = __builtin_amdgcn_mfma_f32_16x16x32_bf16(
                    aF[cur][0][rt], bF0, acc[rt][ct], 0, 0, 0);
                acc[rt][ct] = __builtin_amdgcn_mfma_f32_16x16x32_bf16(
                    aF[cur][0][rt], bF1, acc[rt][ct], 0, 0, 0);
                acc[rt][ct] = __builtin_amdgcn_mfma_f32_16x16x32_bf16(
                    aF[cur][0][rt], bG2[ct], acc[rt][ct], 0, 0, 0);
                acc[rt][ct] = __builtin_amdgcn_mfma_f32_16x16x32_bf16(
                    aF[cur][1][rt], bF0, acc[rt][ct], 0, 0, 0);
                acc[rt][ct] = __builtin_amdgcn_mfma_f32_16x16x32_bf16(
                    aF[cur][1][rt], bF1, acc[rt][ct], 0, 0, 0);
                acc[rt][ct] = __builtin_amdgcn_mfma_f32_16x16x32_bf16(
                    aF[cur][2][rt], bF0, acc[rt][ct], 0, 0, 0);
            }
            // re-issue this ct's B-limb2 fragment for the next chunk right
            // after its last use: nearly a full sweep of latency cover
            if (q < 3)
                bG2[ct] = *(const bf8*)
                    (H + (size_t)(bG2base + ct * 2048 + (q + 1) * 32));
        }
        __builtin_amdgcn_s_setprio(0);

        // WAR barrier only while a future stage will write buf[cur]:
        // stage(q+2) exists iff q+2 <= 3, i.e. q < 2.
        if (q < 2) {
            asm volatile("" ::: "memory");
            __builtin_amdgcn_s_barrier();
            __builtin_amdgcn_sched_barrier(0);
        }
    }

    // ---- epilogue: stash prefetched sq/labels, then mine ----
    sqS[t] = psq; lbS[t] = plb;
    __syncthreads();
    const float* sqI = sqS;       const float* sqJ = sqS + 128;
    const int*   lbI = lbS;       const int*   lbJ = lbS + 128;

    float sjv[8]; int ljv[8];
#pragma unroll
    for (int ct = 0; ct < 8; ++ct) {
        sjv[ct] = sqJ[ct * 16 + l16];
        ljv[ct] = lbJ[ct * 16 + l16];
    }
    // d2 in place
#pragma unroll
    for (int rt = 0; rt < 2; ++rt)
#pragma unroll
        for (int r = 0; r < 4; ++r) {
            const float si = sqI[w * 32 + rt * 16 + quad * 4 + r];
#pragma unroll
            for (int ct = 0; ct < 8; ++ct)
                acc[rt][ct][r] = fmaxf(si + sjv[ct] - 2.0f * acc[rt][ct][r], 0.0f);
        }

    // I-side (diag-specialized): per row scan 8 cols, butterfly l16 lanes.
#pragma unroll
    for (int rt = 0; rt < 2; ++rt)
#pragma unroll
        for (int r = 0; r < 4; ++r) {
            const int lr = w * 32 + rt * 16 + quad * 4 + r;
            const int grow = I0 + lr;
            const int liv = lbI[lr];
            float bpv = -1.0f, bnv = INFINITY; int bpj = 0, bnj = 0;
            if (diag) {
#pragma unroll
                for (int ct = 0; ct < 8; ++ct) {
                    const float d2 = acc[rt][ct][r];
                    const int col = J0 + ct * 16 + l16;
                    const bool same = (liv == ljv[ct]);
                    const float vp = (same && grow != col) ? d2 : 0.0f;
                    if (vp > bpv) { bpv = vp; bpj = col; }
                    const float vn = same ? INFINITY : d2;
                    if (vn < bnv) { bnv = vn; bnj = col; }
                }
            } else {
#pragma unroll
                for (int ct = 0; ct < 8; ++ct) {
                    const float d2 = acc[rt][ct][r];
                    const int col = J0 + ct * 16 + l16;
                    const bool same = (liv == ljv[ct]);
                    const float vp = same ? d2 : 0.0f;
                    if (vp > bpv) { bpv = vp; bpj = col; }
                    const float vn = same ? INFINITY : d2;
                    if (vn < bnv) { bnv = vn; bnj = col; }
                }
            }
            red_max(bpv, bpj, 1); red_max(bpv, bpj, 2);
            red_max(bpv, bpj, 4); red_max(bpv, bpj, 8);
            red_min(bnv, bnj, 1); red_min(bnv, bnj, 2);
            red_min(bnv, bnj, 4); red_min(bnv, bnj, 8);
            if (l16 == 0) {
                atomicMax(&pos_pack[grow], pack_pos(bpv, bpj));
                atomicMin(&neg_pack[grow], pack_neg(bnv, bnj));
            }
        }

    // J-side (skip on diagonal): per col best over this lane's 8 rows,
    // butterfly over quad (16,32), cross-wave merge via LDS, one commit/col.
    if (!diag) {
        float bpv[8], bnv[8]; int bpj[8], bnj[8];
#pragma unroll
        for (int ct = 0; ct < 8; ++ct) {
            bpv[ct] = -1.0f; bpj[ct] = 0; bnv[ct] = INFINITY; bnj[ct] = 0;
#pragma unroll
            for (int rt = 0; rt < 2; ++rt)
#pragma unroll
                for (int r = 0; r < 4; ++r) {
                    const int lr = w * 32 + rt * 16 + quad * 4 + r;
                    const float d2 = acc[rt][ct][r];
                    const int row = I0 + lr;
                    const bool same = (lbI[lr] == ljv[ct]);
                    const float vp = same ? d2 : 0.0f;
                    if (vp > bpv[ct]) { bpv[ct] = vp; bpj[ct] = row; }
                    const float vn = same ? INFINITY : d2;
                    if (vn < bnv[ct]) { bnv[ct] = vn; bnj[ct] = row; }
                }
#pragma unroll
            for (int m = 16; m < 64; m <<= 1) {
                red_max(bpv[ct], bpj[ct], m);
                red_min(bnv[ct], bnj[ct], m);
            }
        }
        // sB is free (all K-loop reads happened before the sqS barrier)
        unsigned long long* scr = (unsigned long long*)sB;
        if (quad == 0) {
#pragma unroll
            for (int ct = 0; ct < 8; ++ct) {
                scr[w * 128 + ct * 16 + l16]       = pack_pos(bpv[ct], bpj[ct]);
                scr[512 + w * 128 + ct * 16 + l16] = pack_neg(bnv[ct], bnj[ct]);
            }
        }
        __syncthreads();
        if (t < 128) {
            unsigned long long mp = 0ULL, mn = ~0ULL;
#pragma unroll
            for (int ww = 0; ww < 4; ++ww) {
                const unsigned long long p = scr[ww * 128 + t];
                const unsigned long long qq = scr[512 + ww * 128 + t];
                if (p > mp) mp = p;
                if (qq < mn) mn = qq;
            }
            atomicMax(&pos_pack[J0 + t], mp);
            atomicMin(&neg_pack[J0 + t], mn);
        }
    }
}

// ---------------------------------------------------------------------------
// Kernel 3: finalize -> int32 outputs [anchor | pos | neg | keep]. (unchanged)
// ---------------------------------------------------------------------------
__global__ void finalize_kernel(const unsigned long long* __restrict__ pos_pack,
                                const unsigned long long* __restrict__ neg_pack,
                                int* __restrict__ out) {
    const int r = blockIdx.x * 256 + threadIdx.x;
    const unsigned long long pp = pos_pack[r];
    const unsigned long long np = neg_pack[r];
    out[r]         = r;
    out[N + r]     = 8191 - (int)(pp & 0xFFFFFFFFULL);
    out[2 * N + r] = (int)(np & 0xFFFFFFFFULL);
    out[3 * N + r] = (pp != 0ULL && np != ~0ULL) ? 1 : 0;
}

extern "C" void kernel_launch(void* const* d_in, const int* in_sizes, int n_in,
                              void* d_out, int out_size, void* d_ws, size_t ws_size,
                              hipStream_t stream) {
    const float* x      = (const float*)d_in[0];
    const int*   labels = (const int*)d_in[1];
    int* out = (int*)d_out;

    short* H = (short*)d_ws;                                // 3*N*D bf16 = 6 MB
    float* sq = (float*)(H + (size_t)3 * N * D);            // N floats
    unsigned long long* pos_pack =
        (unsigned long long*)(sq + N);                      // N u64
    unsigned long long* neg_pack = pos_pack + N;            // N u64

    prep_kernel<<<N / 32, 256, 0, stream>>>(x, H, sq, pos_pack, neg_pack);
    miner_kernel<<<NBLK, 256, 0, stream>>>(H, sq, labels, pos_pack, neg_pack);
    finalize_kernel<<<N / 256, 256, 0, stream>>>(pos_pack, neg_pack, out);
}

// Round 4
// 145.436 us; speedup vs baseline: 1.2941x; 1.2941x over previous
//
#include <hip/hip_runtime.h>
#include <math.h>

#define N 8192
#define D 128
#define NT 64                    // 128-wide tiles per dim
#define NBLK (NT * (NT + 1) / 2) // 2080

typedef __attribute__((ext_vector_type(8))) short bf8;   // 8 bf16 = 4 VGPRs
typedef __attribute__((ext_vector_type(4))) float f4;    // MFMA acc

__device__ __forceinline__ unsigned short bf16_rtne(float f) {
    unsigned u = __float_as_uint(f);
    u += 0x7FFF + ((u >> 16) & 1);
    return (unsigned short)(u >> 16);
}
__device__ __forceinline__ float bf16_tof(unsigned short h) {
    return __uint_as_float((unsigned)h << 16);
}

__device__ __forceinline__ void async_cp16(const void* g, void* l) {
    __builtin_amdgcn_global_load_lds(
        (const __attribute__((address_space(1))) unsigned*)g,
        (__attribute__((address_space(3))) unsigned*)l, 16, 0, 0);
}

// ---------------------------------------------------------------------------
// Kernel 1: normalize + 3-limb bf16 split; 32 rows/block. (unchanged, verified)
// ---------------------------------------------------------------------------
__global__ __launch_bounds__(256) void prep_kernel(
    const float* __restrict__ x, short* __restrict__ H,
    float* __restrict__ sq,
    unsigned long long* __restrict__ pos_pack,
    unsigned long long* __restrict__ neg_pack) {
    __shared__ float Xs[32 * 129];
    const int t = threadIdx.x;
    const int r0 = blockIdx.x * 32;

    if (t < 32) { pos_pack[r0 + t] = 0ULL; neg_pack[r0 + t] = ~0ULL; }

#pragma unroll
    for (int p = 0; p < 4; ++p) {
        const int lin = p * 256 + t;
        const int row = lin >> 5;
        const int c0 = (lin & 31) << 2;
        const float4 v = *(const float4*)(x + (size_t)(r0 + row) * D + c0);
        float* dst = &Xs[row * 129 + c0];
        dst[0] = v.x; dst[1] = v.y; dst[2] = v.z; dst[3] = v.w;
    }
    __syncthreads();

    const int r = t >> 3, q8 = t & 7;
    float* src = &Xs[r * 129 + q8 * 16];
    float s = 0.f;
#pragma unroll
    for (int i = 0; i < 16; ++i) s = fmaf(src[i], src[i], s);
    s += __shfl_xor(s, 1, 64);
    s += __shfl_xor(s, 2, 64);
    s += __shfl_xor(s, 4, 64);
    const float nrm = sqrtf(s);
    float t2 = 0.f;
#pragma unroll
    for (int i = 0; i < 16; ++i) {
        const float n = src[i] / nrm;
        src[i] = n;
        t2 = fmaf(n, n, t2);
    }
    t2 += __shfl_xor(t2, 1, 64);
    t2 += __shfl_xor(t2, 2, 64);
    t2 += __shfl_xor(t2, 4, 64);
    if (q8 == 0) sq[r0 + r] = t2;

    const size_t gbase = (size_t)(r0 + r) * D + q8 * 16;
#pragma unroll
    for (int g = 0; g < 4; ++g) {
        short4 o1, o2, o3;
        short* p1 = (short*)&o1; short* p2 = (short*)&o2; short* p3 = (short*)&o3;
#pragma unroll
        for (int i = 0; i < 4; ++i) {
            const float n = src[g * 4 + i];
            const unsigned short h1 = bf16_rtne(n);
            const float r1 = n - bf16_tof(h1);
            const unsigned short h2 = bf16_rtne(r1);
            const float r2 = r1 - bf16_tof(h2);
            const unsigned short h3 = bf16_rtne(r2);
            p1[i] = (short)h1; p2[i] = (short)h2; p3[i] = (short)h3;
        }
        *(short4*)(H + gbase + g * 4)                     = o1;
        *(short4*)(H + (size_t)N * D + gbase + g * 4)     = o2;
        *(short4*)(H + (size_t)2 * N * D + gbase + g * 4) = o3;
    }
}

// ---------------------------------------------------------------------------
// Kernel 2: symmetric 128x128-tile Gram via 3-limb bf16 mfma_16x16x32.
// R17: occupancy fix. R16 post-mortem: register file binds occupancy
// (arch 112-116 + 64 AGPR acc = 176-180 -> 2 waves/SIMD; per-SIMD pool is
// 512 regs). K-loop reverted to the verified R15 structure (3-limb LDS,
// deep A-pipeline, vmcnt(12) ledger). Epilogue register high-water cut:
// J-side reduction scalarized+fused (-28), sjv scoped to d2 loop (-8),
// aGoff 6->3. __launch_bounds__(256,3) pins 3 blocks/CU (12 waves).
// MFMA accumulation order bitwise-identical to the verified kernel.
// ---------------------------------------------------------------------------
__device__ __forceinline__ unsigned int fbits(float f) {
    union { float f; unsigned int u; } x; x.f = f; return x.u;
}
__device__ __forceinline__ unsigned long long pack_pos(float v, int j) {
    return ((unsigned long long)fbits(v) << 32) | (unsigned int)(8191 - j);
}
__device__ __forceinline__ unsigned long long pack_neg(float v, int j) {
    return ((unsigned long long)fbits(v) << 32) | (unsigned int)j;
}
__device__ __forceinline__ void red_max(float& v, int& j, int mask) {
    const float ov = __shfl_xor(v, mask, 64);
    const int   oj = __shfl_xor(j, mask, 64);
    if (ov > v || (ov == v && oj < j)) { v = ov; j = oj; }
}
__device__ __forceinline__ void red_min(float& v, int& j, int mask) {
    const float ov = __shfl_xor(v, mask, 64);
    const int   oj = __shfl_xor(j, mask, 64);
    if (ov < v || (ov == v && oj < j)) { v = ov; j = oj; }
}

__global__ __launch_bounds__(256, 3) void miner_kernel(
    const short* __restrict__ H, const float* __restrict__ sq,
    const int* __restrict__ labels,
    unsigned long long* __restrict__ pos_pack,
    unsigned long long* __restrict__ neg_pack) {
    // B double-buffer: [2][3 limb][128 smp][32 k] shorts = 49152 B.
    __shared__ __align__(16) short sB[2 * 12288];
    __shared__ float sqS[256];   // [0:128)=sqI, [128:256)=sqJ
    __shared__ int   lbS[256];   // [0:128)=lbI, [128:256)=lbJ

    const int t = threadIdx.x;
    const int w = t >> 6;       // wave id: rows w*32..w*32+31
    const int l = t & 63;
    const int quad = l >> 4;
    const int l16 = l & 15;

    // decode upper-triangular (bi, bj), bi <= bj, NT=64
    const int b = blockIdx.x;
    int bi = (int)((129.0f - sqrtf(16641.0f - 8.0f * (float)b)) * 0.5f);
    while (bi > 0 && (bi * NT - bi * (bi - 1) / 2) > b) --bi;
    while (((bi + 1) * NT - (bi + 1) * bi / 2) <= b) ++bi;
    const int bj = bi + (b - (bi * NT - bi * (bi - 1) / 2));
    const int I0 = bi * 128, J0 = bj * 128;
    const bool diag = (bi == bj);

    // sq/labels prefetch: latency hidden under the entire K-loop
    float psq; int plb;
    {
        const int idx = ((t < 128) ? I0 : J0) + (t & 127);
        psq = sq[idx]; plb = labels[idx];
    }

    // B staging offsets: 6 x 16B per thread per chunk (limb = p>>1).
    int gOffB[6], lOffB[6];
#pragma unroll
    for (int p = 0; p < 6; ++p) {
        const int limb = p >> 1;
        const int c2   = (p & 1) * 256 + t;
        const int smp  = c2 >> 2;
        const int sub  = c2 & 3;
        gOffB[p] = limb * (N * D) + (J0 + smp) * D + sub * 8;
        lOffB[p] = (limb * 128 + smp) * 32 + sub * 8;
    }
    // A fragment global offsets, rt=0 only (rt=1 derived: +16*D = 2048)
    int aGoff[3];
#pragma unroll
    for (int la = 0; la < 3; ++la)
        aGoff[la] = la * (N * D) + (I0 + w * 32 + l16) * D + quad * 8;

    f4 acc[2][8];
#pragma unroll
    for (int rt = 0; rt < 2; ++rt)
#pragma unroll
        for (int ct = 0; ct < 8; ++ct) acc[rt][ct] = (f4){0.f, 0.f, 0.f, 0.f};

    // prologue: stage chunk 0 (6 DMA) + A frags chunk 0 (6 reg loads)
    bf8 aF[2][3][2];
#pragma unroll
    for (int p = 0; p < 6; ++p)
        async_cp16(H + (size_t)gOffB[p], sB + lOffB[p]);
#pragma unroll
    for (int la = 0; la < 3; ++la)
#pragma unroll
        for (int rt = 0; rt < 2; ++rt)
            aF[0][la][rt] = *(const bf8*)(H + (size_t)(aGoff[la] + rt * 2048));

#pragma unroll
    for (int q = 0; q < 4; ++q) {
        const int cur = q & 1, nxt = cur ^ 1;
        const short* sBc = sB + cur * 12288;

        if (q < 3) {
            // issue next chunk's B-stage AND A-frag loads; they stay in
            // flight through this chunk's MFMA phase (true 1-deep pipeline)
            short* sBn = sB + nxt * 12288;
            const int kn = (q + 1) * 32;
#pragma unroll
            for (int p = 0; p < 6; ++p)
                async_cp16(H + (size_t)(gOffB[p] + kn), sBn + lOffB[p]);
#pragma unroll
            for (int la = 0; la < 3; ++la)
#pragma unroll
                for (int rt = 0; rt < 2; ++rt)
                    aF[nxt][la][rt] = *(const bf8*)
                        (H + (size_t)(aGoff[la] + rt * 2048 + kn));
            // drain all but the newest 12 (= stage(q+1)+aF(q+1)); the
            // drained set was issued one full compute phase ago
            asm volatile("s_waitcnt vmcnt(12)" ::: "memory");
        } else {
            asm volatile("s_waitcnt vmcnt(0)" ::: "memory");
        }
        __builtin_amdgcn_s_barrier();          // all waves: sBc fully staged
        __builtin_amdgcn_sched_barrier(0);     // no ds_read hoisting above

        __builtin_amdgcn_s_setprio(1);
#pragma unroll
        for (int ct = 0; ct < 8; ++ct) {
            bf8 bF[3];
#pragma unroll
            for (int lb = 0; lb < 3; ++lb)
                bF[lb] = *(const bf8*)
                    &sBc[(lb * 128 + ct * 16 + l16) * 32 + quad * 8];
#pragma unroll
            for (int rt = 0; rt < 2; ++rt) {
                acc[rt][ct] = __builtin_amdgcn_mfma_f32_16x16x32_bf16(
                    aF[cur][0][rt], bF[0], acc[rt][ct], 0, 0, 0);
                acc[rt][ct] = __builtin_amdgcn_mfma_f32_16x16x32_bf16(
                    aF[cur][0][rt], bF[1], acc[rt][ct], 0, 0, 0);
                acc[rt][ct] = __builtin_amdgcn_mfma_f32_16x16x32_bf16(
                    aF[cur][0][rt], bF[2], acc[rt][ct], 0, 0, 0);
                acc[rt][ct] = __builtin_amdgcn_mfma_f32_16x16x32_bf16(
                    aF[cur][1][rt], bF[0], acc[rt][ct], 0, 0, 0);
                acc[rt][ct] = __builtin_amdgcn_mfma_f32_16x16x32_bf16(
                    aF[cur][1][rt], bF[1], acc[rt][ct], 0, 0, 0);
                acc[rt][ct] = __builtin_amdgcn_mfma_f32_16x16x32_bf16(
                    aF[cur][2][rt], bF[0], acc[rt][ct], 0, 0, 0);
            }
        }
        __builtin_amdgcn_s_setprio(0);

        // WAR barrier only while a future stage will write buf[cur]:
        // stage(q+2) exists iff q+2 <= 3, i.e. q < 2.
        if (q < 2) {
            asm volatile("" ::: "memory");
            __builtin_amdgcn_s_barrier();
            __builtin_amdgcn_sched_barrier(0);
        }
    }

    // ---- epilogue: stash prefetched sq/labels, then mine ----
    sqS[t] = psq; lbS[t] = plb;
    __syncthreads();
    const float* sqI = sqS;       const float* sqJ = sqS + 128;
    const int*   lbI = lbS;       const int*   lbJ = lbS + 128;

    int ljv[8];
#pragma unroll
    for (int ct = 0; ct < 8; ++ct) ljv[ct] = lbJ[ct * 16 + l16];

    // d2 in place; sjv scoped here so its 8 regs die before the mining loops
    {
        float sjv[8];
#pragma unroll
        for (int ct = 0; ct < 8; ++ct) sjv[ct] = sqJ[ct * 16 + l16];
#pragma unroll
        for (int rt = 0; rt < 2; ++rt)
#pragma unroll
            for (int r = 0; r < 4; ++r) {
                const float si = sqI[w * 32 + rt * 16 + quad * 4 + r];
#pragma unroll
                for (int ct = 0; ct < 8; ++ct)
                    acc[rt][ct][r] =
                        fmaxf(si + sjv[ct] - 2.0f * acc[rt][ct][r], 0.0f);
            }
    }

    // I-side (diag-specialized): per row scan 8 cols, butterfly l16 lanes.
#pragma unroll
    for (int rt = 0; rt < 2; ++rt)
#pragma unroll
        for (int r = 0; r < 4; ++r) {
            const int lr = w * 32 + rt * 16 + quad * 4 + r;
            const int grow = I0 + lr;
            const int liv = lbI[lr];
            float bpv = -1.0f, bnv = INFINITY; int bpj = 0, bnj = 0;
            if (diag) {
#pragma unroll
                for (int ct = 0; ct < 8; ++ct) {
                    const float d2 = acc[rt][ct][r];
                    const int col = J0 + ct * 16 + l16;
                    const bool same = (liv == ljv[ct]);
                    const float vp = (same && grow != col) ? d2 : 0.0f;
                    if (vp > bpv) { bpv = vp; bpj = col; }
                    const float vn = same ? INFINITY : d2;
                    if (vn < bnv) { bnv = vn; bnj = col; }
                }
            } else {
#pragma unroll
                for (int ct = 0; ct < 8; ++ct) {
                    const float d2 = acc[rt][ct][r];
                    const int col = J0 + ct * 16 + l16;
                    const bool same = (liv == ljv[ct]);
                    const float vp = same ? d2 : 0.0f;
                    if (vp > bpv) { bpv = vp; bpj = col; }
                    const float vn = same ? INFINITY : d2;
                    if (vn < bnv) { bnv = vn; bnj = col; }
                }
            }
            red_max(bpv, bpj, 1); red_max(bpv, bpj, 2);
            red_max(bpv, bpj, 4); red_max(bpv, bpj, 8);
            red_min(bnv, bnj, 1); red_min(bnv, bnj, 2);
            red_min(bnv, bnj, 4); red_min(bnv, bnj, 8);
            if (l16 == 0) {
                atomicMax(&pos_pack[grow], pack_pos(bpv, bpj));
                atomicMin(&neg_pack[grow], pack_neg(bnv, bnj));
            }
        }

    // J-side (skip on diagonal): per col best over this lane's 8 rows,
    // butterfly over quad (16,32), cross-wave merge via LDS, one commit/col.
    // Scalarized per-ct (reduction + write fused) to cut the register
    // high-water: no bpv[8]/bnv[8]/bpj[8]/bnj[8] arrays.
    if (!diag) {
        // sB is free (all K-loop reads happened before the sqS barrier)
        unsigned long long* scr = (unsigned long long*)sB;
#pragma unroll
        for (int ct = 0; ct < 8; ++ct) {
            float bpv = -1.0f, bnv = INFINITY; int bpj = 0, bnj = 0;
#pragma unroll
            for (int rt = 0; rt < 2; ++rt)
#pragma unroll
                for (int r = 0; r < 4; ++r) {
                    const int lr = w * 32 + rt * 16 + quad * 4 + r;
                    const float d2 = acc[rt][ct][r];
                    const int row = I0 + lr;
                    const bool same = (lbI[lr] == ljv[ct]);
                    const float vp = same ? d2 : 0.0f;
                    if (vp > bpv) { bpv = vp; bpj = row; }
                    const float vn = same ? INFINITY : d2;
                    if (vn < bnv) { bnv = vn; bnj = row; }
                }
            red_max(bpv, bpj, 16); red_min(bnv, bnj, 16);
            red_max(bpv, bpj, 32); red_min(bnv, bnj, 32);
            if (quad == 0) {
                scr[w * 128 + ct * 16 + l16]       = pack_pos(bpv, bpj);
                scr[512 + w * 128 + ct * 16 + l16] = pack_neg(bnv, bnj);
            }
        }
        __syncthreads();
        if (t < 128) {
            unsigned long long mp = 0ULL, mn = ~0ULL;
#pragma unroll
            for (int ww = 0; ww < 4; ++ww) {
                const unsigned long long p = scr[ww * 128 + t];
                const unsigned long long qq = scr[512 + ww * 128 + t];
                if (p > mp) mp = p;
                if (qq < mn) mn = qq;
            }
            atomicMax(&pos_pack[J0 + t], mp);
            atomicMin(&neg_pack[J0 + t], mn);
        }
    }
}

// ---------------------------------------------------------------------------
// Kernel 3: finalize -> int32 outputs [anchor | pos | neg | keep]. (unchanged)
// ---------------------------------------------------------------------------
__global__ void finalize_kernel(const unsigned long long* __restrict__ pos_pack,
                                const unsigned long long* __restrict__ neg_pack,
                                int* __restrict__ out) {
    const int r = blockIdx.x * 256 + threadIdx.x;
    const unsigned long long pp = pos_pack[r];
    const unsigned long long np = neg_pack[r];
    out[r]         = r;
    out[N + r]     = 8191 - (int)(pp & 0xFFFFFFFFULL);
    out[2 * N + r] = (int)(np & 0xFFFFFFFFULL);
    out[3 * N + r] = (pp != 0ULL && np != ~0ULL) ? 1 : 0;
}

extern "C" void kernel_launch(void* const* d_in, const int* in_sizes, int n_in,
                              void* d_out, int out_size, void* d_ws, size_t ws_size,
                              hipStream_t stream) {
    const float* x      = (const float*)d_in[0];
    const int*   labels = (const int*)d_in[1];
    int* out = (int*)d_out;

    short* H = (short*)d_ws;                                // 3*N*D bf16 = 6 MB
    float* sq = (float*)(H + (size_t)3 * N * D);            // N floats
    unsigned long long* pos_pack =
        (unsigned long long*)(sq + N);                      // N u64
    unsigned long long* neg_pack = pos_pack + N;            // N u64

    prep_kernel<<<N / 32, 256, 0, stream>>>(x, H, sq, pos_pack, neg_pack);
    miner_kernel<<<NBLK, 256, 0, stream>>>(H, sq, labels, pos_pack, neg_pack);
    finalize_kernel<<<N / 256, 256, 0, stream>>>(pos_pack, neg_pack, out);
}